// Round 9
// baseline (175.248 us; speedup 1.0000x reference)
//
#include <hip/hip_runtime.h>
#include <hip/hip_bf16.h>

// SSIM loss, round 16: DIAGNOSTIC A/B. Six falsified mechanism theories
// (scratch, depth, coalescing, TLB, LDS-DMA, step-count); all our read
// kernels sit at 1.8-2.2 B/cy/CU while hblur reads at ~2-5x that with the
// SAME per-wave shape (16x1KB burst -> LDS -> barrier -> MFMA). Remaining
// differences: (1) source d_in vs d_ws-just-written, (2) consume side.
// This round launches vpass's exact staging block as a standalone probe
// TWICE, differing ONLY in source pointer: probe_pred reads pred (d_in),
// probe_feat reads feat (d_ws). 512 blocks each, fully resident, XOR
// readback to a dead ws sink. hblur + vpass verbatim r15 (passing anchors).
// Pre-committed readout: pred-fast/feat-slow => ws/dirty-line cause;
// both-slow => staging structure; both-fast => consume side.

typedef float  f32x4  __attribute__((ext_vector_type(4)));
typedef short  short8 __attribute__((ext_vector_type(8)));
typedef short  short4v __attribute__((ext_vector_type(4)));
typedef unsigned int u32x4 __attribute__((ext_vector_type(4)));

__device__ __forceinline__ short bf16s(float x) {
    __hip_bfloat16 h = __float2bfloat16(x);
    return __builtin_bit_cast(short, h);
}
__device__ __forceinline__ float bf16f(float x) {
    unsigned u = (unsigned)__builtin_bit_cast(unsigned short,
                                              __float2bfloat16(x)) << 16;
    return __builtin_bit_cast(float, u);
}

#define SSIM_W_INIT const float W[11] = { \
    0.00102840f, 0.00759876f, 0.03600077f, 0.10936070f, 0.21300554f, \
    0.26601173f, \
    0.21300554f, 0.10936070f, 0.03600077f, 0.00759876f, 0.00102840f}

#define BW_INIT short8 bw; _Pragma("unroll") \
    for (int j = 0; j < 8; ++j) { \
        const int d = quad * 8 + j - n - 3; \
        bw[j] = bf16s((d >= 0 && d <= 10) ? W[d] : 0.f); \
    }

// ============================ PASS 1: hblur =============================
// (verbatim r13/r14/r15)
__global__ __launch_bounds__(256, 2)
void ssim_hblur(const float* __restrict__ pred, const float* __restrict__ targ,
                unsigned short* __restrict__ feat) {
    SSIM_W_INIT;
    __shared__ __align__(16) short featLds[4][16][72][8];  // 73,728 B

    const int w = threadIdx.x >> 6, L = threadIdx.x & 63;
    const int n = L & 15, quad = L >> 4;
    const int img = blockIdx.x >> 5, T = blockIdx.x & 31;

    if (threadIdx.x < 128) {
        const int f = threadIdx.x >> 5, r = (threadIdx.x >> 1) & 15;
        const int gz = (threadIdx.x & 1) ? 65 : 0;
        const short8 z = {0, 0, 0, 0, 0, 0, 0, 0};
        *(short8*)&featLds[f][r][gz ^ (r & 7)][0] = z;
    }

    BW_INIT;
    const f32x4 zc = {0.f, 0.f, 0.f, 0.f};

    const size_t rowbase = (size_t)img * 262144 + (size_t)(16 * T + w * 4) * 512;
    const float* pr = pred + rowbase + 4 * L;
    const float* tr = targ + rowbase + 4 * L;
    const f32x4 pA0 = *(const f32x4*)(pr);
    const f32x4 pB0 = *(const f32x4*)(pr + 256);
    const f32x4 tA0 = *(const f32x4*)(tr);
    const f32x4 tB0 = *(const f32x4*)(tr + 256);
    const f32x4 pA1 = *(const f32x4*)(pr + 512);
    const f32x4 pB1 = *(const f32x4*)(pr + 768);
    const f32x4 tA1 = *(const f32x4*)(tr + 512);
    const f32x4 tB1 = *(const f32x4*)(tr + 768);
    const f32x4 pA2 = *(const f32x4*)(pr + 1024);
    const f32x4 pB2 = *(const f32x4*)(pr + 1280);
    const f32x4 tA2 = *(const f32x4*)(tr + 1024);
    const f32x4 tB2 = *(const f32x4*)(tr + 1280);
    const f32x4 pA3 = *(const f32x4*)(pr + 1536);
    const f32x4 pB3 = *(const f32x4*)(pr + 1792);
    const f32x4 tA3 = *(const f32x4*)(tr + 1536);
    const f32x4 tB3 = *(const f32x4*)(tr + 1792);

    const int gA = 1 + (L >> 1), gB = 33 + (L >> 1), hh = (L & 1) * 4;

#define P1ROW(k, PV, TV, QV, UV)                                          \
    {                                                                     \
        const int r = w * 4 + k;                                          \
        const int m = r & 7;                                              \
        short4v s0, s1, s2, s3, q0, q1, q2, q3;                           \
        _Pragma("unroll") for (int j = 0; j < 4; ++j) {                   \
            const float p = PV[j], t = TV[j];                             \
            const float u = p + t, v = p - t;                             \
            s0[j] = bf16s(p); s1[j] = bf16s(t);                           \
            s2[j] = bf16s(u * u); s3[j] = bf16s(v * v);                   \
            const float p2 = QV[j], t2 = UV[j];                           \
            const float u2 = p2 + t2, v2 = p2 - t2;                       \
            q0[j] = bf16s(p2); q1[j] = bf16s(t2);                         \
            q2[j] = bf16s(u2 * u2); q3[j] = bf16s(v2 * v2);               \
        }                                                                 \
        *(short4v*)&featLds[0][r][gA ^ m][hh] = s0;                       \
        *(short4v*)&featLds[1][r][gA ^ m][hh] = s1;                       \
        *(short4v*)&featLds[2][r][gA ^ m][hh] = s2;                       \
        *(short4v*)&featLds[3][r][gA ^ m][hh] = s3;                       \
        *(short4v*)&featLds[0][r][gB ^ m][hh] = q0;                       \
        *(short4v*)&featLds[1][r][gB ^ m][hh] = q1;                       \
        *(short4v*)&featLds[2][r][gB ^ m][hh] = q2;                       \
        *(short4v*)&featLds[3][r][gB ^ m][hh] = q3;                       \
    }
    P1ROW(0, pA0, tA0, pB0, tB0)
    P1ROW(1, pA1, tA1, pB1, tB1)
    P1ROW(2, pA2, tA2, pB2, tB2)
    P1ROW(3, pA3, tA3, pB3, tB3)
#undef P1ROW

    __syncthreads();

#pragma unroll
    for (int oi = 0; oi < 8; ++oi) {
        const int O = w * 8 + oi;
        unsigned short* dst = feat +
            ((size_t)(img * 32 + O) * 32 + T) * 1024 +
            (quad >> 1) * 512 + n * 8 + (quad & 1) * 4;
#pragma unroll
        for (int f = 0; f < 4; ++f) {
            const short8 af =
                *(const short8*)&featLds[f][n][(2 * O + quad) ^ (n & 7)][0];
            const f32x4 d = __builtin_amdgcn_mfma_f32_16x16x32_bf16(
                af, bw, zc, 0, 0, 0);
            short4v o;
#pragma unroll
            for (int r2 = 0; r2 < 4; ++r2) o[r2] = bf16s(d[r2]);
            *(short4v*)(dst + f * 128) = o;
        }
    }
}

// ======================= PASS 2: vblur + SSIM ===========================
// (verbatim r15 -- the 61us anchor)
__global__ __launch_bounds__(256, 2)
void ssim_vpass(const unsigned short* __restrict__ feat,
                float* __restrict__ slotSum, unsigned int* __restrict__ grpCnt,
                unsigned int* __restrict__ finalCnt, float* __restrict__ out) {
    SSIM_W_INIT;
    __shared__ __align__(16) char strip[66 * 1056];   // 69,696 B
    __shared__ float wsum[4];

    const int w = threadIdx.x >> 6, L = threadIdx.x & 63;
    const int n = L & 15, quad = L >> 4;
    const int img = blockIdx.x >> 5, stripe = blockIdx.x & 31;

    float S = 0.f;
#pragma unroll
    for (int kk = 0; kk < 11; ++kk) S += bf16f(W[kk]);
    const float c2 = 1.0f / (S * S);
    BW_INIT;
    const f32x4 zc = {0.f, 0.f, 0.f, 0.f};

    if (threadIdx.x < 132) {
        const int sl = (threadIdx.x < 66) ? 0 : 65;
        const int of = (threadIdx.x < 66 ? threadIdx.x : threadIdx.x - 66) * 16;
        const short8 z = {0, 0, 0, 0, 0, 0, 0, 0};
        *(short8*)(strip + sl * 1056 + of) = z;
    }

    const unsigned short* gp =
        feat + (size_t)(img * 32 + stripe) * 32768 + w * 8192 + L * 8;
    char* lb = strip + (16 * w + 1) * 1056 + L * 16;

    short8 V0, V1, V2, V3, V4, V5, V6, V7;
    V0 = *(const short8*)(gp);
    V1 = *(const short8*)(gp + 512);
    V2 = *(const short8*)(gp + 1024);
    V3 = *(const short8*)(gp + 1536);
    V4 = *(const short8*)(gp + 2048);
    V5 = *(const short8*)(gp + 2560);
    V6 = *(const short8*)(gp + 3072);
    V7 = *(const short8*)(gp + 3584);
    *(short8*)(lb + 0 * 1056) = V0;
    *(short8*)(lb + 1 * 1056) = V1;
    *(short8*)(lb + 2 * 1056) = V2;
    *(short8*)(lb + 3 * 1056) = V3;
    V0 = *(const short8*)(gp + 4096);
    V1 = *(const short8*)(gp + 4608);
    V2 = *(const short8*)(gp + 5120);
    V3 = *(const short8*)(gp + 5632);
    *(short8*)(lb + 4 * 1056) = V4;
    *(short8*)(lb + 5 * 1056) = V5;
    *(short8*)(lb + 6 * 1056) = V6;
    *(short8*)(lb + 7 * 1056) = V7;
    V4 = *(const short8*)(gp + 6144);
    V5 = *(const short8*)(gp + 6656);
    V6 = *(const short8*)(gp + 7168);
    V7 = *(const short8*)(gp + 7680);
    *(short8*)(lb + 8 * 1056) = V0;
    *(short8*)(lb + 9 * 1056) = V1;
    *(short8*)(lb + 10 * 1056) = V2;
    *(short8*)(lb + 11 * 1056) = V3;
    *(short8*)(lb + 12 * 1056) = V4;
    *(short8*)(lb + 13 * 1056) = V5;
    *(short8*)(lb + 14 * 1056) = V6;
    *(short8*)(lb + 15 * 1056) = V7;

    __syncthreads();

    float lsum = 0.f;
#pragma unroll
    for (int si = 0; si < 8; ++si) {
        const int s = 8 * w + si;
        f32x4 dv[4];
#pragma unroll
        for (int f = 0; f < 4; ++f) {
            const short8 af = *(const short8*)(
                strip + (2 * s + quad) * 1056 + f * 256 + n * 16);
            dv[f] = __builtin_amdgcn_mfma_f32_16x16x32_bf16(af, bw, zc, 0, 0, 0);
        }
#pragma unroll
        for (int r = 0; r < 4; ++r) {
            const float m1 = dv[0][r] * c2, m2 = dv[1][r] * c2;
            const float Av = dv[2][r] * c2, Bv = dv[3][r] * c2;
            const float m12  = m1 * m2;
            const float smsq = m1 * m1 + m2 * m2;
            const float s12  = __builtin_fmaf(0.25f, Av - Bv, -m12);
            const float s1s2 = __builtin_fmaf(0.5f,  Av + Bv, -smsq);
            const float num = __builtin_fmaf(2.f, m12, 1e-4f) *
                              __builtin_fmaf(2.f, s12, 9e-4f);
            const float den = (smsq + 1e-4f) * (s1s2 + 9e-4f);
            float rc = __builtin_amdgcn_rcpf(den);
            rc = rc * (2.f - den * rc);
            lsum = __builtin_fmaf(num, rc, lsum);
        }
    }

#pragma unroll
    for (int off = 32; off > 0; off >>= 1)
        lsum += __shfl_down(lsum, off, 64);
    if (L == 0) wsum[w] = lsum;
    __syncthreads();
    if (threadIdx.x == 0) {
        const float bs = wsum[0] + wsum[1] + wsum[2] + wsum[3];
        const int g = blockIdx.x & 63;
        atomicAdd(&slotSum[g * 16], bs);
        __threadfence();
        if (atomicAdd(&grpCnt[g * 16], 1u) == 15u) {
            __threadfence();
            if (atomicAdd(finalCnt, 1u) == 63u) {
                float s = 0.f;
#pragma unroll
                for (int i = 0; i < 64; ++i)
                    s += atomicAdd(&slotSum[i * 16], 0.f);
                out[0] = 1.0f - s * (1.0f / 8388608.0f);
            }
        }
    }
}

// ====================== PROBE: staging-only clone =======================
// vpass's staging block verbatim; source pointer is the ONLY variable.
// 512 blocks (fully resident, one generation). XOR readback -> dead sink.
__global__ __launch_bounds__(256, 2)
void ssim_probe(const unsigned short* __restrict__ src,
                unsigned int* __restrict__ sink) {
    __shared__ __align__(16) char strip[66 * 1056];   // 69,696 B

    const int w = threadIdx.x >> 6, L = threadIdx.x & 63;
    const unsigned short* gp =
        src + (size_t)blockIdx.x * 32768 + w * 8192 + L * 8;
    char* lb = strip + (16 * w + 1) * 1056 + L * 16;

    short8 V0, V1, V2, V3, V4, V5, V6, V7;
    V0 = *(const short8*)(gp);
    V1 = *(const short8*)(gp + 512);
    V2 = *(const short8*)(gp + 1024);
    V3 = *(const short8*)(gp + 1536);
    V4 = *(const short8*)(gp + 2048);
    V5 = *(const short8*)(gp + 2560);
    V6 = *(const short8*)(gp + 3072);
    V7 = *(const short8*)(gp + 3584);
    *(short8*)(lb + 0 * 1056) = V0;
    *(short8*)(lb + 1 * 1056) = V1;
    *(short8*)(lb + 2 * 1056) = V2;
    *(short8*)(lb + 3 * 1056) = V3;
    V0 = *(const short8*)(gp + 4096);
    V1 = *(const short8*)(gp + 4608);
    V2 = *(const short8*)(gp + 5120);
    V3 = *(const short8*)(gp + 5632);
    *(short8*)(lb + 4 * 1056) = V4;
    *(short8*)(lb + 5 * 1056) = V5;
    *(short8*)(lb + 6 * 1056) = V6;
    *(short8*)(lb + 7 * 1056) = V7;
    V4 = *(const short8*)(gp + 6144);
    V5 = *(const short8*)(gp + 6656);
    V6 = *(const short8*)(gp + 7168);
    V7 = *(const short8*)(gp + 7680);
    *(short8*)(lb + 8 * 1056) = V0;
    *(short8*)(lb + 9 * 1056) = V1;
    *(short8*)(lb + 10 * 1056) = V2;
    *(short8*)(lb + 11 * 1056) = V3;
    *(short8*)(lb + 12 * 1056) = V4;
    *(short8*)(lb + 13 * 1056) = V5;
    *(short8*)(lb + 14 * 1056) = V6;
    *(short8*)(lb + 15 * 1056) = V7;

    __syncthreads();

    u32x4 acc = {0u, 0u, 0u, 0u};
#pragma unroll
    for (int i = 0; i < 16; ++i)
        acc ^= *(const u32x4*)(lb + i * 1056);
    const unsigned int a = acc[0] ^ acc[1] ^ acc[2] ^ acc[3];
    if (L == 0) sink[blockIdx.x * 4 + w] = a;
}

extern "C" void kernel_launch(void* const* d_in, const int* in_sizes, int n_in,
                              void* d_out, int out_size, void* d_ws,
                              size_t ws_size, hipStream_t stream) {
    const float* pred = (const float*)d_in[0];
    const float* targ = (const float*)d_in[1];
    // ws: [0,4096) slotSum @64B stride; [4096,8192) grpCnt; [8192,8196)
    // finalCnt; [16384,24576) probe sink A; [24576,32768) probe sink B;
    // [65536, 65536+64MB) feat intermediate.
    float* slotSum = (float*)d_ws;
    unsigned int* grpCnt = (unsigned int*)((char*)d_ws + 4096);
    unsigned int* finalCnt = (unsigned int*)((char*)d_ws + 8192);
    unsigned int* sinkA = (unsigned int*)((char*)d_ws + 16384);
    unsigned int* sinkB = (unsigned int*)((char*)d_ws + 24576);

    hipMemsetAsync(d_ws, 0, 8196, stream);
    unsigned short* feat = (unsigned short*)((char*)d_ws + 65536);
    ssim_hblur<<<dim3(1024), dim3(256), 0, stream>>>(pred, targ, feat);
    ssim_vpass<<<dim3(1024), dim3(256), 0, stream>>>(feat, slotSum, grpCnt,
                                                     finalCnt, (float*)d_out);
    // A/B probes (after vpass so they don't warm its caches):
    // probe 1: reads pred (d_in). probe 2: reads feat (d_ws, just written).
    ssim_probe<<<dim3(512), dim3(256), 0, stream>>>(
        (const unsigned short*)pred, sinkA);
    ssim_probe<<<dim3(512), dim3(256), 0, stream>>>(feat, sinkB);
    (void)in_sizes; (void)n_in; (void)out_size; (void)ws_size;
}

// Round 10
// 118.853 us; speedup vs baseline: 1.4745x; 1.4745x over previous
//
#include <hip/hip_runtime.h>
#include <hip/hip_bf16.h>

// SSIM loss, round 17: ELIMINATE THE ATOMIC TAIL.
// r16's A/B probes: vpass's staging block verbatim runs ~5us/32MB (~6 TB/s)
// from BOTH pred (d_in) and feat (d_ws). Staging is fast; consume arithmetic
// is ~3us. The one component every 50-90us kernel shares and every fast
// kernel lacks: the device-atomic reduction tail (1024 slot atomicAdds,
// grpCnt cascade + threadfences, 64 serialized finalCnt atomics, then 64
// DEPENDENT atomic reads by one thread ~= 24us alone). Previous session
// already measured a single-address atomic tail at ~150us of 165.
// Fix: vpass stores one plain float per block to partial[bid]; a 1-block
// finish kernel (vec loads + shuffle reduce, ~3us) produces out[0].
// hblur / vpass staging / vstep / SSIM math byte-identical to r15.
// hipMemsetAsync removed (no atomic state to zero).

typedef float  f32x4  __attribute__((ext_vector_type(4)));
typedef short  short8 __attribute__((ext_vector_type(8)));
typedef short  short4v __attribute__((ext_vector_type(4)));

__device__ __forceinline__ short bf16s(float x) {
    __hip_bfloat16 h = __float2bfloat16(x);
    return __builtin_bit_cast(short, h);
}
__device__ __forceinline__ float bf16f(float x) {
    unsigned u = (unsigned)__builtin_bit_cast(unsigned short,
                                              __float2bfloat16(x)) << 16;
    return __builtin_bit_cast(float, u);
}

#define SSIM_W_INIT const float W[11] = { \
    0.00102840f, 0.00759876f, 0.03600077f, 0.10936070f, 0.21300554f, \
    0.26601173f, \
    0.21300554f, 0.10936070f, 0.03600077f, 0.00759876f, 0.00102840f}

#define BW_INIT short8 bw; _Pragma("unroll") \
    for (int j = 0; j < 8; ++j) { \
        const int d = quad * 8 + j - n - 3; \
        bw[j] = bf16s((d >= 0 && d <= 10) ? W[d] : 0.f); \
    }

// ============================ PASS 1: hblur =============================
// (verbatim r13-r16)
__global__ __launch_bounds__(256, 2)
void ssim_hblur(const float* __restrict__ pred, const float* __restrict__ targ,
                unsigned short* __restrict__ feat) {
    SSIM_W_INIT;
    __shared__ __align__(16) short featLds[4][16][72][8];  // 73,728 B

    const int w = threadIdx.x >> 6, L = threadIdx.x & 63;
    const int n = L & 15, quad = L >> 4;
    const int img = blockIdx.x >> 5, T = blockIdx.x & 31;

    if (threadIdx.x < 128) {
        const int f = threadIdx.x >> 5, r = (threadIdx.x >> 1) & 15;
        const int gz = (threadIdx.x & 1) ? 65 : 0;
        const short8 z = {0, 0, 0, 0, 0, 0, 0, 0};
        *(short8*)&featLds[f][r][gz ^ (r & 7)][0] = z;
    }

    BW_INIT;
    const f32x4 zc = {0.f, 0.f, 0.f, 0.f};

    const size_t rowbase = (size_t)img * 262144 + (size_t)(16 * T + w * 4) * 512;
    const float* pr = pred + rowbase + 4 * L;
    const float* tr = targ + rowbase + 4 * L;
    const f32x4 pA0 = *(const f32x4*)(pr);
    const f32x4 pB0 = *(const f32x4*)(pr + 256);
    const f32x4 tA0 = *(const f32x4*)(tr);
    const f32x4 tB0 = *(const f32x4*)(tr + 256);
    const f32x4 pA1 = *(const f32x4*)(pr + 512);
    const f32x4 pB1 = *(const f32x4*)(pr + 768);
    const f32x4 tA1 = *(const f32x4*)(tr + 512);
    const f32x4 tB1 = *(const f32x4*)(tr + 768);
    const f32x4 pA2 = *(const f32x4*)(pr + 1024);
    const f32x4 pB2 = *(const f32x4*)(pr + 1280);
    const f32x4 tA2 = *(const f32x4*)(tr + 1024);
    const f32x4 tB2 = *(const f32x4*)(tr + 1280);
    const f32x4 pA3 = *(const f32x4*)(pr + 1536);
    const f32x4 pB3 = *(const f32x4*)(pr + 1792);
    const f32x4 tA3 = *(const f32x4*)(tr + 1536);
    const f32x4 tB3 = *(const f32x4*)(tr + 1792);

    const int gA = 1 + (L >> 1), gB = 33 + (L >> 1), hh = (L & 1) * 4;

#define P1ROW(k, PV, TV, QV, UV)                                          \
    {                                                                     \
        const int r = w * 4 + k;                                          \
        const int m = r & 7;                                              \
        short4v s0, s1, s2, s3, q0, q1, q2, q3;                           \
        _Pragma("unroll") for (int j = 0; j < 4; ++j) {                   \
            const float p = PV[j], t = TV[j];                             \
            const float u = p + t, v = p - t;                             \
            s0[j] = bf16s(p); s1[j] = bf16s(t);                           \
            s2[j] = bf16s(u * u); s3[j] = bf16s(v * v);                   \
            const float p2 = QV[j], t2 = UV[j];                           \
            const float u2 = p2 + t2, v2 = p2 - t2;                       \
            q0[j] = bf16s(p2); q1[j] = bf16s(t2);                         \
            q2[j] = bf16s(u2 * u2); q3[j] = bf16s(v2 * v2);               \
        }                                                                 \
        *(short4v*)&featLds[0][r][gA ^ m][hh] = s0;                       \
        *(short4v*)&featLds[1][r][gA ^ m][hh] = s1;                       \
        *(short4v*)&featLds[2][r][gA ^ m][hh] = s2;                       \
        *(short4v*)&featLds[3][r][gA ^ m][hh] = s3;                       \
        *(short4v*)&featLds[0][r][gB ^ m][hh] = q0;                       \
        *(short4v*)&featLds[1][r][gB ^ m][hh] = q1;                       \
        *(short4v*)&featLds[2][r][gB ^ m][hh] = q2;                       \
        *(short4v*)&featLds[3][r][gB ^ m][hh] = q3;                       \
    }
    P1ROW(0, pA0, tA0, pB0, tB0)
    P1ROW(1, pA1, tA1, pB1, tB1)
    P1ROW(2, pA2, tA2, pB2, tB2)
    P1ROW(3, pA3, tA3, pB3, tB3)
#undef P1ROW

    __syncthreads();

#pragma unroll
    for (int oi = 0; oi < 8; ++oi) {
        const int O = w * 8 + oi;
        unsigned short* dst = feat +
            ((size_t)(img * 32 + O) * 32 + T) * 1024 +
            (quad >> 1) * 512 + n * 8 + (quad & 1) * 4;
#pragma unroll
        for (int f = 0; f < 4; ++f) {
            const short8 af =
                *(const short8*)&featLds[f][n][(2 * O + quad) ^ (n & 7)][0];
            const f32x4 d = __builtin_amdgcn_mfma_f32_16x16x32_bf16(
                af, bw, zc, 0, 0, 0);
            short4v o;
#pragma unroll
            for (int r2 = 0; r2 < 4; ++r2) o[r2] = bf16s(d[r2]);
            *(short4v*)(dst + f * 128) = o;
        }
    }
}

// ======================= PASS 2: vblur + SSIM ===========================
// (staging + consume verbatim r15; tail = ONE plain store per block)
__global__ __launch_bounds__(256, 2)
void ssim_vpass(const unsigned short* __restrict__ feat,
                float* __restrict__ partial) {
    SSIM_W_INIT;
    __shared__ __align__(16) char strip[66 * 1056];   // 69,696 B
    __shared__ float wsum[4];

    const int w = threadIdx.x >> 6, L = threadIdx.x & 63;
    const int n = L & 15, quad = L >> 4;
    const int img = blockIdx.x >> 5, stripe = blockIdx.x & 31;

    float S = 0.f;
#pragma unroll
    for (int kk = 0; kk < 11; ++kk) S += bf16f(W[kk]);
    const float c2 = 1.0f / (S * S);
    BW_INIT;
    const f32x4 zc = {0.f, 0.f, 0.f, 0.f};

    if (threadIdx.x < 132) {
        const int sl = (threadIdx.x < 66) ? 0 : 65;
        const int of = (threadIdx.x < 66 ? threadIdx.x : threadIdx.x - 66) * 16;
        const short8 z = {0, 0, 0, 0, 0, 0, 0, 0};
        *(short8*)(strip + sl * 1056 + of) = z;
    }

    const unsigned short* gp =
        feat + (size_t)(img * 32 + stripe) * 32768 + w * 8192 + L * 8;
    char* lb = strip + (16 * w + 1) * 1056 + L * 16;

    short8 V0, V1, V2, V3, V4, V5, V6, V7;
    V0 = *(const short8*)(gp);
    V1 = *(const short8*)(gp + 512);
    V2 = *(const short8*)(gp + 1024);
    V3 = *(const short8*)(gp + 1536);
    V4 = *(const short8*)(gp + 2048);
    V5 = *(const short8*)(gp + 2560);
    V6 = *(const short8*)(gp + 3072);
    V7 = *(const short8*)(gp + 3584);
    *(short8*)(lb + 0 * 1056) = V0;
    *(short8*)(lb + 1 * 1056) = V1;
    *(short8*)(lb + 2 * 1056) = V2;
    *(short8*)(lb + 3 * 1056) = V3;
    V0 = *(const short8*)(gp + 4096);
    V1 = *(const short8*)(gp + 4608);
    V2 = *(const short8*)(gp + 5120);
    V3 = *(const short8*)(gp + 5632);
    *(short8*)(lb + 4 * 1056) = V4;
    *(short8*)(lb + 5 * 1056) = V5;
    *(short8*)(lb + 6 * 1056) = V6;
    *(short8*)(lb + 7 * 1056) = V7;
    V4 = *(const short8*)(gp + 6144);
    V5 = *(const short8*)(gp + 6656);
    V6 = *(const short8*)(gp + 7168);
    V7 = *(const short8*)(gp + 7680);
    *(short8*)(lb + 8 * 1056) = V0;
    *(short8*)(lb + 9 * 1056) = V1;
    *(short8*)(lb + 10 * 1056) = V2;
    *(short8*)(lb + 11 * 1056) = V3;
    *(short8*)(lb + 12 * 1056) = V4;
    *(short8*)(lb + 13 * 1056) = V5;
    *(short8*)(lb + 14 * 1056) = V6;
    *(short8*)(lb + 15 * 1056) = V7;

    __syncthreads();

    float lsum = 0.f;
#pragma unroll
    for (int si = 0; si < 8; ++si) {
        const int s = 8 * w + si;
        f32x4 dv[4];
#pragma unroll
        for (int f = 0; f < 4; ++f) {
            const short8 af = *(const short8*)(
                strip + (2 * s + quad) * 1056 + f * 256 + n * 16);
            dv[f] = __builtin_amdgcn_mfma_f32_16x16x32_bf16(af, bw, zc, 0, 0, 0);
        }
#pragma unroll
        for (int r = 0; r < 4; ++r) {
            const float m1 = dv[0][r] * c2, m2 = dv[1][r] * c2;
            const float Av = dv[2][r] * c2, Bv = dv[3][r] * c2;
            const float m12  = m1 * m2;
            const float smsq = m1 * m1 + m2 * m2;
            const float s12  = __builtin_fmaf(0.25f, Av - Bv, -m12);
            const float s1s2 = __builtin_fmaf(0.5f,  Av + Bv, -smsq);
            const float num = __builtin_fmaf(2.f, m12, 1e-4f) *
                              __builtin_fmaf(2.f, s12, 9e-4f);
            const float den = (smsq + 1e-4f) * (s1s2 + 9e-4f);
            float rc = __builtin_amdgcn_rcpf(den);
            rc = rc * (2.f - den * rc);
            lsum = __builtin_fmaf(num, rc, lsum);
        }
    }

#pragma unroll
    for (int off = 32; off > 0; off >>= 1)
        lsum += __shfl_down(lsum, off, 64);
    if (L == 0) wsum[w] = lsum;
    __syncthreads();
    if (threadIdx.x == 0)
        partial[blockIdx.x] = wsum[0] + wsum[1] + wsum[2] + wsum[3];
}

// ========================= PASS 3: finish ==============================
// 1 block x 256 threads: reduce 1024 partials -> out[0]. ~3us.
__global__ __launch_bounds__(256)
void ssim_finish(const float* __restrict__ partial, float* __restrict__ out) {
    __shared__ float ws2[4];
    const int t = threadIdx.x;
    const f32x4 v = *(const f32x4*)(partial + 4 * t);
    float s = v[0] + v[1] + v[2] + v[3];
#pragma unroll
    for (int off = 32; off > 0; off >>= 1)
        s += __shfl_down(s, off, 64);
    if ((t & 63) == 0) ws2[t >> 6] = s;
    __syncthreads();
    if (t == 0)
        out[0] = 1.0f - (ws2[0] + ws2[1] + ws2[2] + ws2[3]) *
                        (1.0f / 8388608.0f);
}

extern "C" void kernel_launch(void* const* d_in, const int* in_sizes, int n_in,
                              void* d_out, int out_size, void* d_ws,
                              size_t ws_size, hipStream_t stream) {
    const float* pred = (const float*)d_in[0];
    const float* targ = (const float*)d_in[1];
    // ws: [0,4096) partial[1024] f32; [65536, 65536+64MB) feat intermediate.
    float* partial = (float*)d_ws;
    unsigned short* feat = (unsigned short*)((char*)d_ws + 65536);

    ssim_hblur<<<dim3(1024), dim3(256), 0, stream>>>(pred, targ, feat);
    ssim_vpass<<<dim3(1024), dim3(256), 0, stream>>>(feat, partial);
    ssim_finish<<<dim3(1), dim3(256), 0, stream>>>(partial, (float*)d_out);
    (void)in_sizes; (void)n_in; (void)out_size; (void)ws_size;
}

// Round 11
// 108.667 us; speedup vs baseline: 1.6127x; 1.0937x over previous
//
#include <hip/hip_runtime.h>
#include <hip/hip_bf16.h>

// SSIM loss, round 18: FUSED single pass (r10 kernel) + plain-store tail.
// r17 confirmed the atomic reduction tail was ~46us of critical path in
// EVERY kernel r7-r15 (vpass 61.7 -> 15us when replaced with plain stores).
// Re-fit of the whole ledger: r10/r11/r12 monolithic = ~20us staging+compute
// + 46us tail -- staging was NEVER the bottleneck, which is why four staging
// rewrites were no-ops. The two-pass r17 (28+15+3 = 46us of kernels) pays an
// extra 64MB write + 64MB read vs fused 128MB read (floor 20.3us @ 6.3TB/s).
// So: r10 monolithic verbatim (gload_lds 2-slot ring, counted vmcnt(4),
// 16-tile strips, no barriers in compute), tail = partial[bid] plain store,
// plus a 1-block finish kernel. No memset, no atomics anywhere.

typedef float  f32x4  __attribute__((ext_vector_type(4)));
typedef short  short8 __attribute__((ext_vector_type(8)));
typedef short  short4v __attribute__((ext_vector_type(4)));

#define NBLOCK 512    // x4 waves = 2048 waves; 2 blk/CU -> whole grid resident

__device__ __forceinline__ short bf16s(float x) {
    __hip_bfloat16 h = __float2bfloat16(x);
    return __builtin_bit_cast(short, h);
}
__device__ __forceinline__ float bf16f(float x) {
    unsigned u = (unsigned)__builtin_bit_cast(unsigned short,
                                              __float2bfloat16(x)) << 16;
    return __builtin_bit_cast(float, u);
}

// one 16B-per-lane async global->LDS copy; lds base wave-uniform, HW lands
// lane L's 16B at base + L*16
__device__ __forceinline__ void gload16(const float* g, float* lds) {
    __builtin_amdgcn_global_load_lds(g, lds, 16, 0, 0);
}

#define WAITV4 asm volatile("s_waitcnt vmcnt(4)" ::: "memory")
#define WAITV0 asm volatile("s_waitcnt vmcnt(0)" ::: "memory")

__global__ __launch_bounds__(256, 2)
void ssim_main(const float* __restrict__ pred, const float* __restrict__ targ,
               float* __restrict__ partial) {
    const float W[11] = {
        0.00102840f, 0.00759876f, 0.03600077f, 0.10936070f, 0.21300554f,
        0.26601173f,
        0.21300554f, 0.10936070f, 0.03600077f, 0.00759876f, 0.00102840f};

    __shared__ __align__(16) short hring[4][4][16][72];   // 36,864 B
    __shared__ __align__(16) float rawbuf[4][2][1024];    // 32,768 B: w,slot
    __shared__ float wsum[4];

    const int w     = threadIdx.x >> 6;
    const int L     = threadIdx.x & 63;
    const int n     = L & 15;
    const int quad  = L >> 4;
    const int waveId = blockIdx.x * 4 + w;
    const int img    = waveId >> 6;          // 32 images
    const int rem    = waveId & 63;
    const int q      = rem >> 5;             // 2 half-image strips
    const int stripe = rem & 31;
    const int c0     = stripe << 4;
    const int s0     = q << 4;               // 16 tiles per strip
    const bool edge  = (stripe == 0) | (stripe == 31);

    const float* __restrict__ pim = pred + (size_t)img * 262144;
    const float* __restrict__ tim = targ + (size_t)img * 262144;

    float S = 0.f;
#pragma unroll
    for (int kk = 0; kk < 11; ++kk) S += bf16f(W[kk]);
    const float c2 = 1.0f / (S * S);

    short8 bw;
#pragma unroll
    for (int j = 0; j < 8; ++j) {
        const int d = quad * 8 + j - n - 3;
        bw[j] = bf16s((d >= 0 && d <= 10) ? W[d] : 0.f);
    }
    const f32x4 zc = {0.f, 0.f, 0.f, 0.f};

    // per-lane source column granules (tile-invariant). cb is a multiple of
    // 8, so each 16B granule is either fully in-bounds or fully out.
    const int  cb  = c0 - 8 + quad * 8;
    const int  cc0 = min(max(cb, 0), 508);
    const int  cc1 = min(max(cb + 4, 0), 508);
    const bool ok0 = (unsigned)cb < 512u;
    const bool ok1 = (unsigned)(cb + 4) < 512u;

    float lsum = 0.f;

    // ---- issue 4 async loads for tile Tt into LDS slot Tt&1 ----
    auto issue = [&](int Tt) {
        const int Tc = min(max(Tt, 0), 31);        // halo tiles: clamped src,
        const int rowoff = ((Tc << 4) + n) * 512;  // data overridden in hproc
        float* sb = &rawbuf[w][Tt & 1][0];
        gload16(pim + rowoff + cc0, sb);           // P granule 0 -> [0,256)
        gload16(pim + rowoff + cc1, sb + 256);     // P granule 1 -> [256,512)
        gload16(tim + rowoff + cc0, sb + 512);     // T granule 0
        gload16(tim + rowoff + cc1, sb + 768);     // T granule 1
    };

    // ---- read slot, cvt + hblur MFMA + ring store (caller waited vmcnt) ----
    auto hproc = [&](int Tt) {
        const int wslot = (int)(((unsigned)(Tt << 4)) & 63u) + quad * 4;
        short4v o[4];
        if ((unsigned)Tt > 31u) {
#pragma unroll
            for (int f = 0; f < 4; ++f) o[f] = (short4v){0, 0, 0, 0};
        } else {
            const float* sb = &rawbuf[w][Tt & 1][0];
            f32x4 p0 = *(const f32x4*)(sb + (L << 2));
            f32x4 p1 = *(const f32x4*)(sb + 256 + (L << 2));
            f32x4 t0 = *(const f32x4*)(sb + 512 + (L << 2));
            f32x4 t1 = *(const f32x4*)(sb + 768 + (L << 2));
            if (edge) {            // wave-uniform branch, per-lane masks
                p0 = ok0 ? p0 : zc;  p1 = ok1 ? p1 : zc;
                t0 = ok0 ? t0 : zc;  t1 = ok1 ? t1 : zc;
            }
            short8 fa[4];
#pragma unroll
            for (int j = 0; j < 4; ++j) {
                const float pj = p0[j], tj = t0[j];
                const float u = pj + tj, v = pj - tj;
                fa[0][j] = bf16s(pj);
                fa[1][j] = bf16s(tj);
                fa[2][j] = bf16s(u * u);
                fa[3][j] = bf16s(v * v);
            }
#pragma unroll
            for (int j = 0; j < 4; ++j) {
                const float pj = p1[j], tj = t1[j];
                const float u = pj + tj, v = pj - tj;
                fa[0][j + 4] = bf16s(pj);
                fa[1][j + 4] = bf16s(tj);
                fa[2][j + 4] = bf16s(u * u);
                fa[3][j + 4] = bf16s(v * v);
            }
#pragma unroll
            for (int f = 0; f < 4; ++f) {
                const f32x4 d = __builtin_amdgcn_mfma_f32_16x16x32_bf16(
                    fa[f], bw, zc, 0, 0, 0);
                short4v ov;
#pragma unroll
                for (int r2 = 0; r2 < 4; ++r2) ov[r2] = bf16s(d[r2]);
                o[f] = ov;
            }
        }
#pragma unroll
        for (int f = 0; f < 4; ++f)
            *(short4v*)&hring[w][f][n][wslot] = o[f];
    };

    // ---- vblur MFMA + SSIM math for output tile s ----
    auto vstep = [&](int s) {
        const int rslot0 = (int)(((unsigned)((s << 4) - 8)) & 63u);
        const int chunk  = (rslot0 + quad * 8) & 63;
        f32x4 dv[4];
#pragma unroll
        for (int f = 0; f < 4; ++f) {
            const short8 af = *(const short8*)&hring[w][f][n][chunk];
            dv[f] = __builtin_amdgcn_mfma_f32_16x16x32_bf16(af, bw, zc, 0, 0, 0);
        }
#pragma unroll
        for (int r = 0; r < 4; ++r) {
            const float m1 = dv[0][r] * c2, m2 = dv[1][r] * c2;
            const float Av = dv[2][r] * c2, Bv = dv[3][r] * c2;
            const float m12  = m1 * m2;
            const float smsq = m1 * m1 + m2 * m2;
            const float s12  = __builtin_fmaf(0.25f, Av - Bv, -m12);
            const float s1s2 = __builtin_fmaf(0.5f,  Av + Bv, -smsq);
            const float num = __builtin_fmaf(2.f, m12, 1e-4f) *
                              __builtin_fmaf(2.f, s12, 9e-4f);
            const float den = (smsq + 1e-4f) * (s1s2 + 9e-4f);
            float rc = __builtin_amdgcn_rcpf(den);
            rc = rc * (2.f - den * rc);
            lsum = __builtin_fmaf(num, rc, lsum);
        }
    };

    // ---- prologue: procs s0-1..s0+1; leaves s0+2, s0+3 in flight ----
    issue(s0 - 1); issue(s0);
    WAITV4; hproc(s0 - 1);
    issue(s0 + 1);
    WAITV4; hproc(s0);
    issue(s0 + 2);
    WAITV4; hproc(s0 + 1);
    issue(s0 + 3);

    // ---- 13 uniform steps: vmcnt(4) keeps one tile always in flight ----
#pragma unroll 1
    for (int s = s0; s < s0 + 13; ++s) {
        vstep(s);
        WAITV4; hproc(s + 2);
        issue(s + 4);
    }
    // ---- tail ----
    vstep(s0 + 13); WAITV4; hproc(s0 + 15);
    vstep(s0 + 14); WAITV0; hproc(s0 + 16);
    vstep(s0 + 15);

    // ---- reduce: plain store, no atomics ----
#pragma unroll
    for (int off = 32; off > 0; off >>= 1)
        lsum += __shfl_down(lsum, off, 64);
    if (L == 0) wsum[w] = lsum;
    __syncthreads();
    if (threadIdx.x == 0)
        partial[blockIdx.x] = wsum[0] + wsum[1] + wsum[2] + wsum[3];
}

// ========================= finish kernel ==============================
// 1 block x 128 threads: reduce 512 partials -> out[0].
__global__ __launch_bounds__(128)
void ssim_finish(const float* __restrict__ partial, float* __restrict__ out) {
    __shared__ float ws2[2];
    const int t = threadIdx.x;
    const f32x4 v = *(const f32x4*)(partial + 4 * t);
    float s = v[0] + v[1] + v[2] + v[3];
#pragma unroll
    for (int off = 32; off > 0; off >>= 1)
        s += __shfl_down(s, off, 64);
    if ((t & 63) == 0) ws2[t >> 6] = s;
    __syncthreads();
    if (t == 0)
        out[0] = 1.0f - (ws2[0] + ws2[1]) * (1.0f / 8388608.0f);
}

extern "C" void kernel_launch(void* const* d_in, const int* in_sizes, int n_in,
                              void* d_out, int out_size, void* d_ws,
                              size_t ws_size, hipStream_t stream) {
    const float* pred = (const float*)d_in[0];
    const float* targ = (const float*)d_in[1];
    // ws: [0,2048) partial[512] f32. No other workspace use, no memset.
    float* partial = (float*)d_ws;

    ssim_main<<<dim3(NBLOCK), dim3(256), 0, stream>>>(pred, targ, partial);
    ssim_finish<<<dim3(1), dim3(128), 0, stream>>>(partial, (float*)d_out);
    (void)in_sizes; (void)n_in; (void)out_size; (void)ws_size;
}

// Round 13
// 104.657 us; speedup vs baseline: 1.6745x; 1.0383x over previous
//
#include <hip/hip_runtime.h>
#include <hip/hip_bf16.h>

// SSIM loss, round 20: r19's register raw pipeline with the SCHEDULE FIXED.
// r19 failed (NaN): vstep(s) needs hring tiles s-1,s,s+1 hproc'd, but the
// r19 prologue only covered through s0 -> first vstep read uninitialized
// LDS. Restored r10's phase: prologue hprocs s0-1,s0,s0+1 (B=s0+2, A=s0+3
// left in flight); loop: vstep(s); HPROC(s+2,B); LOADT(B,s+4); vstep(s+1);
// HPROC(s+3,A); LOADT(A,s+5). Ring slot aliasing verified (writer (s+2)&3
// disjoint from reader {s-1,s,s+1}&3). Everything else r19-identical:
// no rawbuf (pure pass-through removed), 2 pending tiles in NAMED f32x4
// regs, plain loads, compiler counted-vmcnt at first use, LDS = hring only
// (37 KB) -> 4 blk/CU = 16 waves/CU; plain-store tail + finish kernel.

typedef float  f32x4  __attribute__((ext_vector_type(4)));
typedef short  short8 __attribute__((ext_vector_type(8)));
typedef short  short4v __attribute__((ext_vector_type(4)));

#define NBLOCK 512    // x4 waves = 2048 waves; 4 blk/CU -> whole grid resident

__device__ __forceinline__ short bf16s(float x) {
    __hip_bfloat16 h = __float2bfloat16(x);
    return __builtin_bit_cast(short, h);
}
__device__ __forceinline__ float bf16f(float x) {
    unsigned u = (unsigned)__builtin_bit_cast(unsigned short,
                                              __float2bfloat16(x)) << 16;
    return __builtin_bit_cast(float, u);
}

__global__ __launch_bounds__(256, 4)
void ssim_main(const float* __restrict__ pred, const float* __restrict__ targ,
               float* __restrict__ partial) {
    const float W[11] = {
        0.00102840f, 0.00759876f, 0.03600077f, 0.10936070f, 0.21300554f,
        0.26601173f,
        0.21300554f, 0.10936070f, 0.03600077f, 0.00759876f, 0.00102840f};

    __shared__ __align__(16) short hring[4][4][16][72];   // 36,864 B
    __shared__ float wsum[4];

    const int w     = threadIdx.x >> 6;
    const int L     = threadIdx.x & 63;
    const int n     = L & 15;
    const int quad  = L >> 4;
    const int waveId = blockIdx.x * 4 + w;
    const int img    = waveId >> 6;          // 32 images
    const int rem    = waveId & 63;
    const int q      = rem >> 5;             // 2 half-image strips
    const int stripe = rem & 31;
    const int c0     = stripe << 4;
    const int s0     = q << 4;               // 16 tiles per strip
    const bool edge  = (stripe == 0) | (stripe == 31);

    const float* __restrict__ pim = pred + (size_t)img * 262144;
    const float* __restrict__ tim = targ + (size_t)img * 262144;

    float S = 0.f;
#pragma unroll
    for (int kk = 0; kk < 11; ++kk) S += bf16f(W[kk]);
    const float c2 = 1.0f / (S * S);

    short8 bw;
#pragma unroll
    for (int j = 0; j < 8; ++j) {
        const int d = quad * 8 + j - n - 3;
        bw[j] = bf16s((d >= 0 && d <= 10) ? W[d] : 0.f);
    }
    const f32x4 zc = {0.f, 0.f, 0.f, 0.f};

    // per-lane source granules (tile-invariant): lane (n,quad) covers cols
    // [c0-8+8q, +8) of row n. cb multiple of 4 -> granule fully in or out.
    const int  cb  = c0 - 8 + quad * 8;
    const int  cc0 = min(max(cb, 0), 508);
    const int  cc1 = min(max(cb + 4, 0), 508);
    const bool ok0 = (unsigned)cb < 512u;
    const bool ok1 = (unsigned)(cb + 4) < 512u;

    float lsum = 0.f;

    // ---- LOADT: 4 plain f32x4 loads for tile Tt into named regs ----
#define LOADT(P0, P1, T0, T1, Tt)                                         \
    {                                                                     \
        const int Tc_ = min(max((Tt), 0), 31);                            \
        const int ro_ = ((Tc_ << 4) + n) * 512;                           \
        P0 = *(const f32x4*)(pim + ro_ + cc0);                            \
        P1 = *(const f32x4*)(pim + ro_ + cc1);                            \
        T0 = *(const f32x4*)(tim + ro_ + cc0);                            \
        T1 = *(const f32x4*)(tim + ro_ + cc1);                            \
    }

    // ---- HPROC: cvt + hblur MFMA + ring store from named regs ----
#define HPROC(Tt, P0, P1, T0, T1)                                         \
    {                                                                     \
        const int wslot_ = (int)(((unsigned)((Tt) << 4)) & 63u) + quad*4; \
        short4v o0_, o1_, o2_, o3_;                                       \
        if ((unsigned)(Tt) > 31u) {                                       \
            o0_ = (short4v){0,0,0,0}; o1_ = o0_; o2_ = o0_; o3_ = o0_;    \
        } else {                                                          \
            f32x4 p0_ = P0, p1_ = P1, t0_ = T0, t1_ = T1;                 \
            if (edge) {                                                   \
                p0_ = ok0 ? p0_ : zc;  p1_ = ok1 ? p1_ : zc;              \
                t0_ = ok0 ? t0_ : zc;  t1_ = ok1 ? t1_ : zc;              \
            }                                                             \
            short8 fa0_, fa1_, fa2_, fa3_;                                \
            _Pragma("unroll") for (int j = 0; j < 4; ++j) {               \
                const float pj_ = p0_[j], tj_ = t0_[j];                   \
                const float u_ = pj_ + tj_, v_ = pj_ - tj_;               \
                fa0_[j] = bf16s(pj_);  fa1_[j] = bf16s(tj_);              \
                fa2_[j] = bf16s(u_*u_); fa3_[j] = bf16s(v_*v_);           \
            }                                                             \
            _Pragma("unroll") for (int j = 0; j < 4; ++j) {               \
                const float pj_ = p1_[j], tj_ = t1_[j];                   \
                const float u_ = pj_ + tj_, v_ = pj_ - tj_;               \
                fa0_[j+4] = bf16s(pj_);  fa1_[j+4] = bf16s(tj_);          \
                fa2_[j+4] = bf16s(u_*u_); fa3_[j+4] = bf16s(v_*v_);       \
            }                                                             \
            f32x4 d_;                                                     \
            d_ = __builtin_amdgcn_mfma_f32_16x16x32_bf16(fa0_,bw,zc,0,0,0);\
            _Pragma("unroll") for (int r_=0;r_<4;++r_) o0_[r_]=bf16s(d_[r_]);\
            d_ = __builtin_amdgcn_mfma_f32_16x16x32_bf16(fa1_,bw,zc,0,0,0);\
            _Pragma("unroll") for (int r_=0;r_<4;++r_) o1_[r_]=bf16s(d_[r_]);\
            d_ = __builtin_amdgcn_mfma_f32_16x16x32_bf16(fa2_,bw,zc,0,0,0);\
            _Pragma("unroll") for (int r_=0;r_<4;++r_) o2_[r_]=bf16s(d_[r_]);\
            d_ = __builtin_amdgcn_mfma_f32_16x16x32_bf16(fa3_,bw,zc,0,0,0);\
            _Pragma("unroll") for (int r_=0;r_<4;++r_) o3_[r_]=bf16s(d_[r_]);\
        }                                                                 \
        *(short4v*)&hring[w][0][n][wslot_] = o0_;                         \
        *(short4v*)&hring[w][1][n][wslot_] = o1_;                         \
        *(short4v*)&hring[w][2][n][wslot_] = o2_;                         \
        *(short4v*)&hring[w][3][n][wslot_] = o3_;                         \
    }

    // ---- vblur MFMA + SSIM math for output tile s ----
    auto vstep = [&](int s) {
        const int rslot0 = (int)(((unsigned)((s << 4) - 8)) & 63u);
        const int chunk  = (rslot0 + quad * 8) & 63;
        f32x4 dv[4];
#pragma unroll
        for (int f = 0; f < 4; ++f) {
            const short8 af = *(const short8*)&hring[w][f][n][chunk];
            dv[f] = __builtin_amdgcn_mfma_f32_16x16x32_bf16(af, bw, zc, 0, 0, 0);
        }
#pragma unroll
        for (int r = 0; r < 4; ++r) {
            const float m1 = dv[0][r] * c2, m2 = dv[1][r] * c2;
            const float Av = dv[2][r] * c2, Bv = dv[3][r] * c2;
            const float m12  = m1 * m2;
            const float smsq = m1 * m1 + m2 * m2;
            const float s12  = __builtin_fmaf(0.25f, Av - Bv, -m12);
            const float s1s2 = __builtin_fmaf(0.5f,  Av + Bv, -smsq);
            const float num = __builtin_fmaf(2.f, m12, 1e-4f) *
                              __builtin_fmaf(2.f, s12, 9e-4f);
            const float den = (smsq + 1e-4f) * (s1s2 + 9e-4f);
            float rc = __builtin_amdgcn_rcpf(den);
            rc = rc * (2.f - den * rc);
            lsum = __builtin_fmaf(num, rc, lsum);
        }
    };

    // two pending tile-buffers in named regs (32 VGPRs)
    f32x4 AP0, AP1, AT0, AT1, BP0, BP1, BT0, BT1;

    // ---- prologue: hproc s0-1, s0, s0+1; leave B=s0+2, A=s0+3 in flight ----
    LOADT(AP0, AP1, AT0, AT1, s0 - 1)
    LOADT(BP0, BP1, BT0, BT1, s0)
    HPROC(s0 - 1, AP0, AP1, AT0, AT1)          // waits A; B in flight
    LOADT(AP0, AP1, AT0, AT1, s0 + 1)
    HPROC(s0, BP0, BP1, BT0, BT1)              // waits B; A in flight
    LOADT(BP0, BP1, BT0, BT1, s0 + 2)
    HPROC(s0 + 1, AP0, AP1, AT0, AT1)          // waits A; B in flight
    LOADT(AP0, AP1, AT0, AT1, s0 + 3)

    // ---- 8 pairs: vstep(s) has s-1..s+1 ready; B holds s+2, A holds s+3 ----
#pragma unroll 1
    for (int i = 0; i < 8; ++i) {
        const int s = s0 + 2 * i;
        vstep(s);
        HPROC(s + 2, BP0, BP1, BT0, BT1)       // waits B; A in flight
        if (i < 7) LOADT(BP0, BP1, BT0, BT1, s + 4)
        vstep(s + 1);
        if (i < 7) {
            HPROC(s + 3, AP0, AP1, AT0, AT1)   // waits A; B in flight
            if (i < 6) LOADT(AP0, AP1, AT0, AT1, s + 5)
        }
    }
    // hproc'd: prologue s0-1..s0+1, B-chain s0+2..s0+16 (even), A-chain
    // s0+3..s0+15 (odd, i<7). vstep(s0+15) needed s0+16 -- done at i=7.

    // ---- reduce: plain store, no atomics ----
#pragma unroll
    for (int off = 32; off > 0; off >>= 1)
        lsum += __shfl_down(lsum, off, 64);
    if (L == 0) wsum[w] = lsum;
    __syncthreads();
    if (threadIdx.x == 0)
        partial[blockIdx.x] = wsum[0] + wsum[1] + wsum[2] + wsum[3];
#undef LOADT
#undef HPROC
}

// ========================= finish kernel ==============================
// 1 block x 128 threads: reduce 512 partials -> out[0].
__global__ __launch_bounds__(128)
void ssim_finish(const float* __restrict__ partial, float* __restrict__ out) {
    __shared__ float ws2[2];
    const int t = threadIdx.x;
    const f32x4 v = *(const f32x4*)(partial + 4 * t);
    float s = v[0] + v[1] + v[2] + v[3];
#pragma unroll
    for (int off = 32; off > 0; off >>= 1)
        s += __shfl_down(s, off, 64);
    if ((t & 63) == 0) ws2[t >> 6] = s;
    __syncthreads();
    if (t == 0)
        out[0] = 1.0f - (ws2[0] + ws2[1]) * (1.0f / 8388608.0f);
}

extern "C" void kernel_launch(void* const* d_in, const int* in_sizes, int n_in,
                              void* d_out, int out_size, void* d_ws,
                              size_t ws_size, hipStream_t stream) {
    const float* pred = (const float*)d_in[0];
    const float* targ = (const float*)d_in[1];
    // ws: [0,2048) partial[512] f32. No memset needed (all 512 written).
    float* partial = (float*)d_ws;

    ssim_main<<<dim3(NBLOCK), dim3(256), 0, stream>>>(pred, targ, partial);
    ssim_finish<<<dim3(1), dim3(128), 0, stream>>>(partial, (float*)d_out);
    (void)in_sizes; (void)n_in; (void)out_size; (void)ws_size;
}